// Round 3
// baseline (250.092 us; speedup 1.0000x reference)
//
#include <hip/hip_runtime.h>

#define Bsz 512
#define Nn  128
#define Dd  256
#define Tt  512

typedef __attribute__((ext_vector_type(8))) short short8;
typedef __attribute__((ext_vector_type(4))) float f32x4;

__device__ __forceinline__ ushort f2bf(float f) {
    union { float f; unsigned u; } v; v.f = f;
    unsigned r = v.u + 0x7fffu + ((v.u >> 16) & 1u);  // RNE
    return (ushort)(r >> 16);
}
__device__ __forceinline__ unsigned pk2(float a, float b) {
    return (unsigned)f2bf(a) | ((unsigned)f2bf(b) << 16);
}
__device__ __forceinline__ float bf2f(ushort u) {
    union { unsigned u; float f; } v; v.u = (unsigned)u << 16; return v.f;
}
__device__ __forceinline__ float dot4(float4 a, float4 b) {
    return a.x * b.x + a.y * b.y + a.z * b.z + a.w * b.w;
}

// reduce a full-wave partial (64 lanes, one row) and write dotL[w + off]
#define RED(p, off) { float v_ = (p); \
    v_ += __shfl_xor(v_, 1);  v_ += __shfl_xor(v_, 2);  v_ += __shfl_xor(v_, 4); \
    v_ += __shfl_xor(v_, 8);  v_ += __shfl_xor(v_, 16); v_ += __shfl_xor(v_, 32); \
    if (lane == 0) dotL[w + (off)] = v_; }

// v3b: 256 blocks x 1024 thr, 1 block/CU, 2 batches/block, cross-batch
// register prefetch so batch1's entire read phase hides under batch0's
// compute/write back-half. (v3 resubmit after infra failure; audited.)
__global__ __launch_bounds__(1024, 4) void mega(
    const float* __restrict__ x, const float* __restrict__ adj,
    const int* __restrict__ head, const float* __restrict__ lin_w,
    const float* __restrict__ bias,
    float* __restrict__ emb, float* __restrict__ nadj)
{
    const int t = threadIdx.x;
    __shared__ __align__(16) ushort adjB[Nn][136];   // 34816 B (-> PT -> xTp)
    __shared__ __align__(16) ushort STl[Nn][136];    // 34816 B
    __shared__ float ttS[Nn], disS[Nn], maskS[Nn], alphaS[Nn], uS[Nn], rowcS[Nn], dotL[Nn];
    __shared__ int   flags[Nn];
    __shared__ int   nuniq;
    __shared__ float cutS;

    const float bias0 = bias[0];
    const int lane = t & 63, w = t >> 6;
    const int l15 = lane & 15, quad = lane >> 4;
    const int mrow  = (w & 7) * 16;
    const int nhalf = (w >> 3) * 64;
    const int r = t >> 3, seg = t & 7;
    const int xrow = t & 127, kq0 = t >> 7;

    float4 pf0 = {0,0,0,0}, pf1 = {0,0,0,0}, pf2 = {0,0,0,0}, pf3 = {0,0,0,0};

    for (int it = 0; it < 2; ++it) {
        const int b = 2 * blockIdx.x + it;

        if (t < Nn) flags[t] = 0;
        if (t == 0) { nuniq = 0; cutS = 0.f; }

        int hv = 0;
        if (t < Tt) hv = head[(size_t)b * Tt + t];

        if (it == 0) {
            // cold start: waves 0-7 x-dot, waves 8-15 adj staging (overlapped)
            if (t < 512) {
                const int dr = t >> 2, dh = t & 3;
                const float4* xr = (const float4*)(x + ((size_t)b * Nn + dr) * Dd + dh * 64);
                const float4* wr = (const float4*)(lin_w + dh * 64);
                float p = 0.f;
#pragma unroll
                for (int i = 0; i < 16; ++i) p += dot4(xr[i], wr[i]);
                p += __shfl_xor(p, 1);
                p += __shfl_xor(p, 2);
                if (dh == 0) dotL[dr] = p;
            } else {
                const int t2 = t - 512;
                const float* adjb = adj + (size_t)b * Nn * Nn;
#pragma unroll
                for (int i = 0; i < 8; ++i) {
                    int f = t2 + 512 * i;
                    int rr2 = f >> 5, c = (f & 31) * 4;
                    float4 v = *(const float4*)&adjb[(size_t)rr2 * Nn + c];
                    uint2 w2; w2.x = pk2(v.x, v.y); w2.y = pk2(v.z, v.w);
                    *(uint2*)&adjB[rr2][c] = w2;
                }
            }
        } else {
            // warm start: stage adj from prefetch regs (f = t + 1024*j); dotL done
            float4 v; int f, rr2, c; uint2 w2;
            v = pf0; f = t;        rr2 = f >> 5; c = (f & 31) * 4; w2.x = pk2(v.x, v.y); w2.y = pk2(v.z, v.w); *(uint2*)&adjB[rr2][c] = w2;
            v = pf1; f = t + 1024; rr2 = f >> 5; c = (f & 31) * 4; w2.x = pk2(v.x, v.y); w2.y = pk2(v.z, v.w); *(uint2*)&adjB[rr2][c] = w2;
            v = pf2; f = t + 2048; rr2 = f >> 5; c = (f & 31) * 4; w2.x = pk2(v.x, v.y); w2.y = pk2(v.z, v.w); *(uint2*)&adjB[rr2][c] = w2;
            v = pf3; f = t + 3072; rr2 = f >> 5; c = (f & 31) * 4; w2.x = pk2(v.x, v.y); w2.y = pk2(v.z, v.w); *(uint2*)&adjB[rr2][c] = w2;
        }
        __syncthreads();                                           // B1

        if (t < Tt) flags[hv] = 1;

        {   // ---- row sums (8 lanes/row, shuffle reduce) ----
            short8 a0 = *(const short8*)&adjB[r][seg * 16];
            short8 a1 = *(const short8*)&adjB[r][seg * 16 + 8];
            float s = 0.f;
#pragma unroll
            for (int j = 0; j < 8; ++j) s += bf2f((ushort)a0[j]) + bf2f((ushort)a1[j]);
            s += __shfl_xor(s, 1); s += __shfl_xor(s, 2); s += __shfl_xor(s, 4);
            if (seg == 0) {
                maskS[r] = (s > 0.f) ? 1.f : 0.f;
                float dis = 1.f / sqrtf(fmaxf(s + 1.f, 1.f));
                disS[r] = dis;
                ttS[r]  = dis * dotL[r];
            }
        }
        __syncthreads();                                           // B2

        {   // ---- matvec adj*tt -> alpha ----
            short8 a0 = *(const short8*)&adjB[r][seg * 16];
            short8 a1 = *(const short8*)&adjB[r][seg * 16 + 8];
            float s = 0.f;
#pragma unroll
            for (int j = 0; j < 8; ++j) {
                s += bf2f((ushort)a0[j]) * ttS[seg * 16 + j];
                s += bf2f((ushort)a1[j]) * ttS[seg * 16 + 8 + j];
            }
            s += __shfl_xor(s, 1); s += __shfl_xor(s, 2); s += __shfl_xor(s, 4);
            if (seg == 0) {
                float o = maskS[r] * disS[r] * (s + ttS[r]) + bias0;
                alphaS[r] = 1.f / (1.f + expf(-o * o));
                atomicAdd(&nuniq, flags[r]);
            }
        }
        __syncthreads();                                           // B3

        {   // ---- k-th largest, parallel rank select (8 thr/row) ----
            int nu = nuniq;
            if (nu > 1) {
                float an = alphaS[r];
                int cg = 0, ce = 0;
                const int j0 = seg * 16;
#pragma unroll
                for (int j = 0; j < 16; ++j) {
                    float aj = alphaS[j0 + j];
                    cg += (aj > an); ce += (aj == an);
                }
                cg += __shfl_xor(cg, 1); cg += __shfl_xor(cg, 2); cg += __shfl_xor(cg, 4);
                ce += __shfl_xor(ce, 1); ce += __shfl_xor(ce, 2); ce += __shfl_xor(ce, 4);
                if (seg == 0) {
                    int idx = (int)ceilf((float)nu * 0.1f);
                    if (idx > Nn - 1) idx = Nn - 1;
                    if (cg <= idx && idx < cg + ce) cutS = an;  // benign same-value race
                }
            }
        }
        __syncthreads();                                           // B4
        if (t < Nn) uS[t] = fmaxf(alphaS[t] + 1e-7f - cutS, 0.f) * disS[t];
        __syncthreads();                                           // B5

        {   // ---- matvec adj*u -> rowc (row L1; all terms >= 0) ----
            short8 a0 = *(const short8*)&adjB[r][seg * 16];
            short8 a1 = *(const short8*)&adjB[r][seg * 16 + 8];
            float s = 0.f;
#pragma unroll
            for (int j = 0; j < 8; ++j) {
                s += bf2f((ushort)a0[j]) * uS[seg * 16 + j];
                s += bf2f((ushort)a1[j]) * uS[seg * 16 + 8 + j];
            }
            s += __shfl_xor(s, 1); s += __shfl_xor(s, 2); s += __shfl_xor(s, 4);
            if (seg == 0) {
                float rsum = maskS[r] * disS[r] * (uS[r] + s);
                rowcS[r]   = maskS[r] * disS[r] / fmaxf(rsum, 1e-12f);
            }
        }
        __syncthreads();                                           // B6

        // ---- build ST[m][k] = rowc_k*(adj[k][m]+delta)*u_m (bf16, LDS) ----
        {
            const int m = t & 127, sl = t >> 7, k0 = sl * 16;
            const float um = uS[m];
            float vv[16];
#pragma unroll
            for (int j = 0; j < 16; ++j) {
                int k = k0 + j;
                vv[j] = rowcS[k] * (bf2f(adjB[k][m]) + ((k == m) ? 1.f : 0.f)) * um;
            }
            uint4 p0, p1;
            p0.x = pk2(vv[0],  vv[1]);  p0.y = pk2(vv[2],  vv[3]);
            p0.z = pk2(vv[4],  vv[5]);  p0.w = pk2(vv[6],  vv[7]);
            p1.x = pk2(vv[8],  vv[9]);  p1.y = pk2(vv[10], vv[11]);
            p1.z = pk2(vv[12], vv[13]); p1.w = pk2(vv[14], vv[15]);
            *(uint4*)&STl[m][k0]     = p0;
            *(uint4*)&STl[m][k0 + 8] = p1;
        }
        __syncthreads();                                           // B7

        if (it == 0) {  // prefetch adj[b+1]: latency/BW hides under G2..G3+stores
            const float4* a1 = (const float4*)(adj + (size_t)(b + 1) * Nn * Nn);
            pf0 = a1[t]; pf1 = a1[t + 1024]; pf2 = a1[t + 2048]; pf3 = a1[t + 3072];
        }

        f32x4 acc[4];
        // ---- G2: P = adj * S ----
#pragma unroll
        for (int nt = 0; nt < 4; ++nt) acc[nt] = (f32x4){0.f, 0.f, 0.f, 0.f};
#pragma unroll
        for (int k0 = 0; k0 < 128; k0 += 32) {
            short8 a0 = *(const short8*)&adjB[mrow + l15][k0 + quad * 8];
#pragma unroll
            for (int nt = 0; nt < 4; ++nt) {
                short8 bf = *(const short8*)&STl[nhalf + nt * 16 + l15][k0 + quad * 8];
                acc[nt] = __builtin_amdgcn_mfma_f32_16x16x32_bf16(a0, bf, acc[nt], 0, 0, 0);
            }
        }
        __syncthreads();                                           // B8: adj bf16 dead

        // ---- write P^T (bf16) into adjB region ----
        ushort (*PT)[136] = (ushort(*)[136])&adjB[0][0];
#pragma unroll
        for (int nt = 0; nt < 4; ++nt) {
            int j    = nhalf + nt * 16 + l15;
            int mcol = mrow + quad * 4;
            uint2 w2;
            w2.x = pk2(acc[nt][0], acc[nt][1]);
            w2.y = pk2(acc[nt][2], acc[nt][3]);
            *(uint2*)&PT[j][mcol] = w2;
        }
        __syncthreads();                                           // B9

        // ---- G3: nadj = S^T P ----
#pragma unroll
        for (int nt = 0; nt < 4; ++nt) acc[nt] = (f32x4){0.f, 0.f, 0.f, 0.f};
#pragma unroll
        for (int k0 = 0; k0 < 128; k0 += 32) {
            short8 a0 = *(const short8*)&STl[mrow + l15][k0 + quad * 8];
#pragma unroll
            for (int nt = 0; nt < 4; ++nt) {
                short8 bf = *(const short8*)&PT[nhalf + nt * 16 + l15][k0 + quad * 8];
                acc[nt] = __builtin_amdgcn_mfma_f32_16x16x32_bf16(a0, bf, acc[nt], 0, 0, 0);
            }
        }
#pragma unroll
        for (int nt = 0; nt < 4; ++nt)
#pragma unroll
            for (int rr2 = 0; rr2 < 4; ++rr2) {
                int row = mrow + quad * 4 + rr2;
                int col = nhalf + nt * 16 + l15;
                nadj[((size_t)b * Nn + row) * Nn + col] = acc[nt][rr2];
            }
        __syncthreads();                                           // B10: PT dead

        // ---- emb = S^T x; x staged bf16 k-pairs xTp[d][kp] in dead region ----
        uint (*xTp)[68] = (uint(*)[68])&adjB[0][0];
        const int dcb = (w >> 3) * 64;
        const float4* xf1 = (const float4*)(x + (size_t)(b + 1) * Nn * Dd);
        float4 wv = ((const float4*)lin_w)[lane];
        float4 qa0 = {0,0,0,0}, qa1 = {0,0,0,0}, qa2 = {0,0,0,0}, qa3 = {0,0,0,0};
        float pA0 = 0.f, pA1 = 0.f, pA2 = 0.f, pA3 = 0.f;
        float pB0 = 0.f, pB1 = 0.f, pB2 = 0.f, pB3 = 0.f;

        if (it == 0) {  // x[b+1] dot, chunk A issue: hides under staging+GEMM h0
            qa0 = xf1[t]; qa1 = xf1[t + 1024]; qa2 = xf1[t + 2048]; qa3 = xf1[t + 3072];
        }

        // half 0 staging (reads L3-warm x, conflict-free LDS writes)
        {
            const float* xb = x + (size_t)b * Nn * Dd + xrow;
            float e[8], g[8];
#pragma unroll
            for (int k = 0; k < 8; ++k) e[k] = xb[(size_t)(8 * kq0 + k) * Dd];
#pragma unroll
            for (int k = 0; k < 8; ++k) g[k] = xb[(size_t)(8 * (kq0 + 8) + k) * Dd];
            uint4 q;
            q.x = pk2(e[0], e[1]); q.y = pk2(e[2], e[3]);
            q.z = pk2(e[4], e[5]); q.w = pk2(e[6], e[7]);
            *(uint4*)&xTp[xrow][4 * kq0] = q;
            q.x = pk2(g[0], g[1]); q.y = pk2(g[2], g[3]);
            q.z = pk2(g[4], g[5]); q.w = pk2(g[6], g[7]);
            *(uint4*)&xTp[xrow][4 * (kq0 + 8)] = q;
        }
        __syncthreads();                                           // B11

        f32x4 accE[4];
#pragma unroll
        for (int nt = 0; nt < 4; ++nt) accE[nt] = (f32x4){0.f, 0.f, 0.f, 0.f};
#pragma unroll
        for (int ks = 0; ks < 4; ++ks) {
            short8 aE = *(const short8*)&STl[mrow + l15][ks * 32 + quad * 8];
#pragma unroll
            for (int nt = 0; nt < 4; ++nt) {
                short8 bf = *(const short8*)&xTp[dcb + nt * 16 + l15][ks * 16 + quad * 4];
                accE[nt] = __builtin_amdgcn_mfma_f32_16x16x32_bf16(aE, bf, accE[nt], 0, 0, 0);
            }
        }
#pragma unroll
        for (int nt = 0; nt < 4; ++nt)
#pragma unroll
            for (int rr2 = 0; rr2 < 4; ++rr2) {
                int row = mrow + quad * 4 + rr2;
                int col = dcb + nt * 16 + l15;
                emb[((size_t)b * Nn + row) * Dd + col] = accE[nt][rr2];
            }
        __syncthreads();                                           // B12

        if (it == 0) {  // consume A, issue chunk B: hides under staging+GEMM h1
            pA0 = dot4(qa0, wv); pA1 = dot4(qa1, wv);
            pA2 = dot4(qa2, wv); pA3 = dot4(qa3, wv);
            qa0 = xf1[t + 4096]; qa1 = xf1[t + 5120];
            qa2 = xf1[t + 6144]; qa3 = xf1[t + 7168];
        }

        // half 1 staging
        {
            const float* xb = x + (size_t)b * Nn * Dd + 128 + xrow;
            float e[8], g[8];
#pragma unroll
            for (int k = 0; k < 8; ++k) e[k] = xb[(size_t)(8 * kq0 + k) * Dd];
#pragma unroll
            for (int k = 0; k < 8; ++k) g[k] = xb[(size_t)(8 * (kq0 + 8) + k) * Dd];
            uint4 q;
            q.x = pk2(e[0], e[1]); q.y = pk2(e[2], e[3]);
            q.z = pk2(e[4], e[5]); q.w = pk2(e[6], e[7]);
            *(uint4*)&xTp[xrow][4 * kq0] = q;
            q.x = pk2(g[0], g[1]); q.y = pk2(g[2], g[3]);
            q.z = pk2(g[4], g[5]); q.w = pk2(g[6], g[7]);
            *(uint4*)&xTp[xrow][4 * (kq0 + 8)] = q;
        }
        __syncthreads();                                           // B13

#pragma unroll
        for (int nt = 0; nt < 4; ++nt) accE[nt] = (f32x4){0.f, 0.f, 0.f, 0.f};
#pragma unroll
        for (int ks = 0; ks < 4; ++ks) {
            short8 aE = *(const short8*)&STl[mrow + l15][ks * 32 + quad * 8];
#pragma unroll
            for (int nt = 0; nt < 4; ++nt) {
                short8 bf = *(const short8*)&xTp[dcb + nt * 16 + l15][ks * 16 + quad * 4];
                accE[nt] = __builtin_amdgcn_mfma_f32_16x16x32_bf16(aE, bf, accE[nt], 0, 0, 0);
            }
        }
#pragma unroll
        for (int nt = 0; nt < 4; ++nt)
#pragma unroll
            for (int rr2 = 0; rr2 < 4; ++rr2) {
                int row = mrow + quad * 4 + rr2;
                int col = 128 + dcb + nt * 16 + l15;
                emb[((size_t)b * Nn + row) * Dd + col] = accE[nt][rr2];
            }

        if (it == 0) {
            // consume chunk B; full-wave reduce (wave w, lane = col4, row = w+16*jj)
            pB0 = dot4(qa0, wv); pB1 = dot4(qa1, wv);
            pB2 = dot4(qa2, wv); pB3 = dot4(qa3, wv);
            RED(pA0, 0)  RED(pA1, 16) RED(pA2, 32) RED(pA3, 48)
            RED(pB0, 64) RED(pB1, 80) RED(pB2, 96) RED(pB3, 112)
            __syncthreads();                                       // B14: iter boundary
        }
    }
}

extern "C" void kernel_launch(void* const* d_in, const int* in_sizes, int n_in,
                              void* d_out, int out_size, void* d_ws, size_t ws_size,
                              hipStream_t stream)
{
    const float* x     = (const float*)d_in[0];
    const float* adj   = (const float*)d_in[1];
    const int*   head  = (const int*)d_in[2];
    const float* lin_w = (const float*)d_in[3];
    const float* bias  = (const float*)d_in[4];

    float* emb  = (float*)d_out;                 // [B,N,D]
    float* nadj = emb + (size_t)Bsz * Nn * Dd;   // [B,N,N]

    mega<<<Bsz / 2, 1024, 0, stream>>>(x, adj, head, lin_w, bias, emb, nadj);
}

// Round 4
// 200.112 us; speedup vs baseline: 1.2498x; 1.2498x over previous
//
#include <hip/hip_runtime.h>

#define Bsz 512
#define Nn  128
#define Dd  256
#define Tt  512

typedef __attribute__((ext_vector_type(8))) short short8;
typedef __attribute__((ext_vector_type(4))) float f32x4;

__device__ __forceinline__ ushort f2bf(float f) {
    union { float f; unsigned u; } v; v.f = f;
    unsigned r = v.u + 0x7fffu + ((v.u >> 16) & 1u);  // RNE
    return (ushort)(r >> 16);
}
__device__ __forceinline__ unsigned pk2(float a, float b) {
    return (unsigned)f2bf(a) | ((unsigned)f2bf(b) << 16);
}
__device__ __forceinline__ float bf2f(ushort u) {
    union { unsigned u; float f; } v; v.u = (unsigned)u << 16; return v.f;
}

// v4: 512 blocks x 1024 thr, 1 batch/block, ~143 KB LDS (1 block/CU).
// Single read burst (x read ONCE, f32 dot folded into staging via wave
// reduction), dedicated xT buffers kill the mid-tail staging phases,
// 8 barriers total, zero cross-phase register hoarding (v3 spill fix).
__global__ __launch_bounds__(1024, 4) void mega(
    const float* __restrict__ x, const float* __restrict__ adj,
    const int* __restrict__ head, const float* __restrict__ lin_w,
    const float* __restrict__ bias,
    float* __restrict__ emb, float* __restrict__ nadj)
{
    const int t = threadIdx.x, b = blockIdx.x;
    __shared__ __align__(16) ushort adjB[Nn][136];   // 34816 B (-> PT after G2)
    __shared__ __align__(16) ushort STl[Nn][136];    // 34816 B
    __shared__ __align__(16) uint   xT0[Nn][68];     // 34816 B  x bf16 pairs, d 0..127
    __shared__ __align__(16) uint   xT1[Nn][68];     // 34816 B  x bf16 pairs, d 128..255
    __shared__ float ttS[Nn], disS[Nn], maskS[Nn], alphaS[Nn], rowcS[Nn];
    __shared__ float dotP2[Nn][2];
    __shared__ int   flags[Nn];
    __shared__ int   nuniq;
    __shared__ float cutS;

    const float bias0 = bias[0];
    if (t < Nn) flags[t] = 0;
    if (t == 0) { nuniq = 0; cutS = 0.f; }

    const int lane = t & 63, w = t >> 6;
    const int l15 = lane & 15, quad = lane >> 4;
    const int mrow  = (w & 7) * 16;
    const int nhalf = (w >> 3) * 64;
    const int r = t >> 3, seg = t & 7;
    const int xrow = t & 127, kq0 = t >> 7;

    int hv = 0;
    if (t < Tt) hv = head[(size_t)b * Tt + t];

    // ================= read burst: x (once) + adj, fully overlapped =========
    float e0[8], g0[8], e1[8], g1[8];
    {
        const float* xb = x + (size_t)b * Nn * Dd + xrow;
#pragma unroll
        for (int k = 0; k < 8; ++k) e0[k] = xb[(size_t)(8 * kq0 + k) * Dd];
#pragma unroll
        for (int k = 0; k < 8; ++k) g0[k] = xb[(size_t)(64 + 8 * kq0 + k) * Dd];
#pragma unroll
        for (int k = 0; k < 8; ++k) e1[k] = xb[(size_t)(8 * kq0 + k) * Dd + 128];
#pragma unroll
        for (int k = 0; k < 8; ++k) g1[k] = xb[(size_t)(64 + 8 * kq0 + k) * Dd + 128];
    }
    float4 av0, av1, av2, av3;
    {
        const float4* adjb = (const float4*)(adj + (size_t)b * Nn * Nn);
        av0 = adjb[t]; av1 = adjb[t + 1024]; av2 = adjb[t + 2048]; av3 = adjb[t + 3072];
    }
    const float wv0 = lin_w[xrow], wv1 = lin_w[128 + xrow];

    // fold f32 lin-dot: wave covers 16 fixed nodes x 64 d-values
#pragma unroll
    for (int k = 0; k < 8; ++k) {
        float re = e0[k] * wv0 + e1[k] * wv1;
        float rg = g0[k] * wv0 + g1[k] * wv1;
        re += __shfl_xor(re, 1); re += __shfl_xor(re, 2); re += __shfl_xor(re, 4);
        re += __shfl_xor(re, 8); re += __shfl_xor(re, 16); re += __shfl_xor(re, 32);
        rg += __shfl_xor(rg, 1); rg += __shfl_xor(rg, 2); rg += __shfl_xor(rg, 4);
        rg += __shfl_xor(rg, 8); rg += __shfl_xor(rg, 16); rg += __shfl_xor(rg, 32);
        if (lane == 0) {
            dotP2[8 * kq0 + k][w & 1]      = re;
            dotP2[64 + 8 * kq0 + k][w & 1] = rg;
        }
    }

    // pack x -> xT0/xT1 (uint at [d][kp] = (x[2kp][d], x[2kp+1][d]))
    {
        uint4 q;
        q.x = pk2(e0[0], e0[1]); q.y = pk2(e0[2], e0[3]);
        q.z = pk2(e0[4], e0[5]); q.w = pk2(e0[6], e0[7]);
        *(uint4*)&xT0[xrow][4 * kq0] = q;
        q.x = pk2(g0[0], g0[1]); q.y = pk2(g0[2], g0[3]);
        q.z = pk2(g0[4], g0[5]); q.w = pk2(g0[6], g0[7]);
        *(uint4*)&xT0[xrow][4 * (kq0 + 8)] = q;
        q.x = pk2(e1[0], e1[1]); q.y = pk2(e1[2], e1[3]);
        q.z = pk2(e1[4], e1[5]); q.w = pk2(e1[6], e1[7]);
        *(uint4*)&xT1[xrow][4 * kq0] = q;
        q.x = pk2(g1[0], g1[1]); q.y = pk2(g1[2], g1[3]);
        q.z = pk2(g1[4], g1[5]); q.w = pk2(g1[6], g1[7]);
        *(uint4*)&xT1[xrow][4 * (kq0 + 8)] = q;
    }
    // pack adj -> adjB (bf16)
    {
        float4 v; int f, rr2, c; uint2 w2;
        v = av0; f = t;        rr2 = f >> 5; c = (f & 31) * 4; w2.x = pk2(v.x, v.y); w2.y = pk2(v.z, v.w); *(uint2*)&adjB[rr2][c] = w2;
        v = av1; f = t + 1024; rr2 = f >> 5; c = (f & 31) * 4; w2.x = pk2(v.x, v.y); w2.y = pk2(v.z, v.w); *(uint2*)&adjB[rr2][c] = w2;
        v = av2; f = t + 2048; rr2 = f >> 5; c = (f & 31) * 4; w2.x = pk2(v.x, v.y); w2.y = pk2(v.z, v.w); *(uint2*)&adjB[rr2][c] = w2;
        v = av3; f = t + 3072; rr2 = f >> 5; c = (f & 31) * 4; w2.x = pk2(v.x, v.y); w2.y = pk2(v.z, v.w); *(uint2*)&adjB[rr2][c] = w2;
    }
    __syncthreads();                                           // B1

    if (t < Tt) flags[hv] = 1;

    {   // ---- row sums (8 lanes/row, shuffle reduce) ----
        short8 a0 = *(const short8*)&adjB[r][seg * 16];
        short8 a1 = *(const short8*)&adjB[r][seg * 16 + 8];
        float s = 0.f;
#pragma unroll
        for (int j = 0; j < 8; ++j) s += bf2f((ushort)a0[j]) + bf2f((ushort)a1[j]);
        s += __shfl_xor(s, 1); s += __shfl_xor(s, 2); s += __shfl_xor(s, 4);
        if (seg == 0) {
            maskS[r] = (s > 0.f) ? 1.f : 0.f;
            float dis = 1.f / sqrtf(fmaxf(s + 1.f, 1.f));
            disS[r] = dis;
            ttS[r]  = dis * (dotP2[r][0] + dotP2[r][1]);
        }
    }
    __syncthreads();                                           // B2

    {   // ---- matvec adj*tt -> alpha ----
        short8 a0 = *(const short8*)&adjB[r][seg * 16];
        short8 a1 = *(const short8*)&adjB[r][seg * 16 + 8];
        float s = 0.f;
#pragma unroll
        for (int j = 0; j < 8; ++j) {
            s += bf2f((ushort)a0[j]) * ttS[seg * 16 + j];
            s += bf2f((ushort)a1[j]) * ttS[seg * 16 + 8 + j];
        }
        s += __shfl_xor(s, 1); s += __shfl_xor(s, 2); s += __shfl_xor(s, 4);
        if (seg == 0) {
            float o = maskS[r] * disS[r] * (s + ttS[r]) + bias0;
            alphaS[r] = 1.f / (1.f + expf(-o * o));
            atomicAdd(&nuniq, flags[r]);
        }
    }
    __syncthreads();                                           // B3

    {   // ---- k-th largest, parallel rank select (8 thr/row) ----
        int nu = nuniq;
        if (nu > 1) {
            float an = alphaS[r];
            int cg = 0, ce = 0;
            const int j0 = seg * 16;
#pragma unroll
            for (int j = 0; j < 16; ++j) {
                float aj = alphaS[j0 + j];
                cg += (aj > an); ce += (aj == an);
            }
            cg += __shfl_xor(cg, 1); cg += __shfl_xor(cg, 2); cg += __shfl_xor(cg, 4);
            ce += __shfl_xor(ce, 1); ce += __shfl_xor(ce, 2); ce += __shfl_xor(ce, 4);
            if (seg == 0) {
                int idx = (int)ceilf((float)nu * 0.1f);
                if (idx > Nn - 1) idx = Nn - 1;
                if (cg <= idx && idx < cg + ce) cutS = an;  // benign same-value race
            }
        }
    }
    __syncthreads();                                           // B4

    {   // ---- matvec adj*u -> rowc; u computed on the fly ----
        const float cut = cutS;
        short8 a0 = *(const short8*)&adjB[r][seg * 16];
        short8 a1 = *(const short8*)&adjB[r][seg * 16 + 8];
        float s = 0.f;
#pragma unroll
        for (int j = 0; j < 8; ++j) {
            int j0 = seg * 16 + j, j1 = seg * 16 + 8 + j;
            float u0 = fmaxf(alphaS[j0] + 1e-7f - cut, 0.f) * disS[j0];
            float u1 = fmaxf(alphaS[j1] + 1e-7f - cut, 0.f) * disS[j1];
            s += bf2f((ushort)a0[j]) * u0 + bf2f((ushort)a1[j]) * u1;
        }
        s += __shfl_xor(s, 1); s += __shfl_xor(s, 2); s += __shfl_xor(s, 4);
        if (seg == 0) {
            float ur   = fmaxf(alphaS[r] + 1e-7f - cut, 0.f) * disS[r];
            float rsum = maskS[r] * disS[r] * (ur + s);
            rowcS[r]   = maskS[r] * disS[r] / fmaxf(rsum, 1e-12f);
        }
    }
    __syncthreads();                                           // B5

    // ---- build ST[m][k] = rowc_k*(adj[k][m]+delta)*u_m (bf16, LDS) ----
    {
        const float cut = cutS;
        const int m = t & 127, sl = t >> 7, k0 = sl * 16;
        const float um = fmaxf(alphaS[m] + 1e-7f - cut, 0.f) * disS[m];
        float vv[16];
#pragma unroll
        for (int j = 0; j < 16; ++j) {
            int k = k0 + j;
            vv[j] = rowcS[k] * (bf2f(adjB[k][m]) + ((k == m) ? 1.f : 0.f)) * um;
        }
        uint4 p0, p1;
        p0.x = pk2(vv[0],  vv[1]);  p0.y = pk2(vv[2],  vv[3]);
        p0.z = pk2(vv[4],  vv[5]);  p0.w = pk2(vv[6],  vv[7]);
        p1.x = pk2(vv[8],  vv[9]);  p1.y = pk2(vv[10], vv[11]);
        p1.z = pk2(vv[12], vv[13]); p1.w = pk2(vv[14], vv[15]);
        *(uint4*)&STl[m][k0]     = p0;
        *(uint4*)&STl[m][k0 + 8] = p1;
    }
    __syncthreads();                                           // B6

    f32x4 acc[4];
    // ---- G2: P = adj * S ----
#pragma unroll
    for (int nt = 0; nt < 4; ++nt) acc[nt] = (f32x4){0.f, 0.f, 0.f, 0.f};
#pragma unroll
    for (int k0 = 0; k0 < 128; k0 += 32) {
        short8 a0 = *(const short8*)&adjB[mrow + l15][k0 + quad * 8];
#pragma unroll
        for (int nt = 0; nt < 4; ++nt) {
            short8 bf = *(const short8*)&STl[nhalf + nt * 16 + l15][k0 + quad * 8];
            acc[nt] = __builtin_amdgcn_mfma_f32_16x16x32_bf16(a0, bf, acc[nt], 0, 0, 0);
        }
    }
    __syncthreads();                                           // B7: adj bf16 dead

    // ---- write P^T (bf16) into adjB region ----
    ushort (*PT)[136] = (ushort(*)[136])&adjB[0][0];
#pragma unroll
    for (int nt = 0; nt < 4; ++nt) {
        int j    = nhalf + nt * 16 + l15;
        int mcol = mrow + quad * 4;
        uint2 w2;
        w2.x = pk2(acc[nt][0], acc[nt][1]);
        w2.y = pk2(acc[nt][2], acc[nt][3]);
        *(uint2*)&PT[j][mcol] = w2;
    }
    __syncthreads();                                           // B8

    // ---- G3: nadj = S^T P ----
#pragma unroll
    for (int nt = 0; nt < 4; ++nt) acc[nt] = (f32x4){0.f, 0.f, 0.f, 0.f};
#pragma unroll
    for (int k0 = 0; k0 < 128; k0 += 32) {
        short8 a0 = *(const short8*)&STl[mrow + l15][k0 + quad * 8];
#pragma unroll
        for (int nt = 0; nt < 4; ++nt) {
            short8 bf = *(const short8*)&PT[nhalf + nt * 16 + l15][k0 + quad * 8];
            acc[nt] = __builtin_amdgcn_mfma_f32_16x16x32_bf16(a0, bf, acc[nt], 0, 0, 0);
        }
    }
#pragma unroll
    for (int nt = 0; nt < 4; ++nt)
#pragma unroll
        for (int rr2 = 0; rr2 < 4; ++rr2) {
            int row = mrow + quad * 4 + rr2;
            int col = nhalf + nt * 16 + l15;
            nadj[((size_t)b * Nn + row) * Nn + col] = acc[nt][rr2];
        }

    // ---- emb = S^T x, both halves straight from xT0/xT1 (no barriers) ----
    const int dcb = (w >> 3) * 64;
    short8 aE[4];
#pragma unroll
    for (int ks = 0; ks < 4; ++ks)
        aE[ks] = *(const short8*)&STl[mrow + l15][ks * 32 + quad * 8];

    f32x4 accE[4];
#pragma unroll
    for (int nt = 0; nt < 4; ++nt) accE[nt] = (f32x4){0.f, 0.f, 0.f, 0.f};
#pragma unroll
    for (int ks = 0; ks < 4; ++ks) {
#pragma unroll
        for (int nt = 0; nt < 4; ++nt) {
            short8 bf = *(const short8*)&xT0[dcb + nt * 16 + l15][ks * 16 + quad * 4];
            accE[nt] = __builtin_amdgcn_mfma_f32_16x16x32_bf16(aE[ks], bf, accE[nt], 0, 0, 0);
        }
    }
#pragma unroll
    for (int nt = 0; nt < 4; ++nt)
#pragma unroll
        for (int rr2 = 0; rr2 < 4; ++rr2) {
            int row = mrow + quad * 4 + rr2;
            int col = dcb + nt * 16 + l15;
            emb[((size_t)b * Nn + row) * Dd + col] = accE[nt][rr2];
        }

#pragma unroll
    for (int nt = 0; nt < 4; ++nt) accE[nt] = (f32x4){0.f, 0.f, 0.f, 0.f};
#pragma unroll
    for (int ks = 0; ks < 4; ++ks) {
#pragma unroll
        for (int nt = 0; nt < 4; ++nt) {
            short8 bf = *(const short8*)&xT1[dcb + nt * 16 + l15][ks * 16 + quad * 4];
            accE[nt] = __builtin_amdgcn_mfma_f32_16x16x32_bf16(aE[ks], bf, accE[nt], 0, 0, 0);
        }
    }
#pragma unroll
    for (int nt = 0; nt < 4; ++nt)
#pragma unroll
        for (int rr2 = 0; rr2 < 4; ++rr2) {
            int row = mrow + quad * 4 + rr2;
            int col = 128 + dcb + nt * 16 + l15;
            emb[((size_t)b * Nn + row) * Dd + col] = accE[nt][rr2];
        }
}

extern "C" void kernel_launch(void* const* d_in, const int* in_sizes, int n_in,
                              void* d_out, int out_size, void* d_ws, size_t ws_size,
                              hipStream_t stream)
{
    const float* x     = (const float*)d_in[0];
    const float* adj   = (const float*)d_in[1];
    const int*   head  = (const int*)d_in[2];
    const float* lin_w = (const float*)d_in[3];
    const float* bias  = (const float*)d_in[4];

    float* emb  = (float*)d_out;                 // [B,N,D]
    float* nadj = emb + (size_t)Bsz * Nn * Dd;   // [B,N,N]

    mega<<<Bsz, 1024, 0, stream>>>(x, adj, head, lin_w, bias, emb, nadj);
}